// Round 10
// baseline (315.532 us; speedup 1.0000x reference)
//
#include <hip/hip_runtime.h>
#include <math.h>

// q,k,v: [B=2, H=16, N=2048, Dh=64] fp32.  BH = 32 independent heads.
#define BH 32
#define NN 2048
#define DD 64
#define BHNN (BH * NN)        // 65536 rows total
#define QK ((size_t)BH * NN * DD)  // 4,194,304 elems per tensor
#define LDK 72                // padded LDS row (ushort): stride 144B, conflict-free (measured 0)

// 8 * log2(e): logits produced in base-2 domain so all softmax exps are a bare
// v_exp_f32 (exp2). Softmax is invariant to the base change.
#define QSCALE 11.5415603f

typedef __attribute__((ext_vector_type(8)))  short shortx8;
typedef __attribute__((ext_vector_type(16))) float floatx16;

__device__ inline float fexp2(float x) { return __builtin_amdgcn_exp2f(x); }

// ---- bf16 split helpers (round-to-nearest-even) -----------------------------
__device__ inline unsigned short bf16_rn(float f) {
    unsigned int u = __builtin_bit_cast(unsigned int, f);
    u += 0x7fffu + ((u >> 16) & 1u);
    return (unsigned short)(u >> 16);
}
__device__ inline float bf16_to_f(unsigned short h) {
    return __builtin_bit_cast(float, (unsigned int)h << 16);
}
__device__ inline void split_bf16(float f, unsigned short& h, unsigned short& l) {
    h = bf16_rn(f);
    l = bf16_rn(f - bf16_to_f(h));
}

// C/D row for accumulator register r (0..15) given half = lane>>5 (verified R2).
__device__ inline int rowmap(int r, int half) {
    return (r & 3) + 8 * (r >> 2) + 4 * half;
}

// ---------------------------------------------------------------------------
// Pre-convert: q,k fp32 -> bf16 hi/lo arrays. QSCALE folded into q.
// ---------------------------------------------------------------------------
__global__ __launch_bounds__(256) void convert_kernel(const float4* __restrict__ q,
                                                      const float4* __restrict__ k,
                                                      ushort* __restrict__ qhi,
                                                      ushort* __restrict__ qlo,
                                                      ushort* __restrict__ khi,
                                                      ushort* __restrict__ klo) {
    size_t gid = (size_t)blockIdx.x * 256 + threadIdx.x;  // float4 index, QK/4 total
    float4 qa = q[gid];
    float4 ka = k[gid];
    ushort4 h, l;
    split_bf16(qa.x * QSCALE, h.x, l.x);
    split_bf16(qa.y * QSCALE, h.y, l.y);
    split_bf16(qa.z * QSCALE, h.z, l.z);
    split_bf16(qa.w * QSCALE, h.w, l.w);
    *(ushort4*)&qhi[gid * 4] = h;
    *(ushort4*)&qlo[gid * 4] = l;
    split_bf16(ka.x, h.x, l.x);
    split_bf16(ka.y, h.y, l.y);
    split_bf16(ka.z, h.z, l.z);
    split_bf16(ka.w, h.w, l.w);
    *(ushort4*)&khi[gid * 4] = h;
    *(ushort4*)&klo[gid * 4] = l;
}

// ---- tile staging: 128 rows x 64 cols bf16 (hi+lo), 16B chunks per thread ----
__device__ inline void load_tile(const ushort* __restrict__ khi_t,
                                 const ushort* __restrict__ klo_t,
                                 int tid, shortx8 rh[4], shortx8 rl[4]) {
#pragma unroll
    for (int i = 0; i < 4; ++i) {
        int c = tid + 256 * i;       // chunk 0..1023
        int r = c >> 3, s = c & 7;   // row, 16B slot
        rh[i] = *(const shortx8*)&khi_t[(size_t)r * 64 + s * 8];
        rl[i] = *(const shortx8*)&klo_t[(size_t)r * 64 + s * 8];
    }
}
__device__ inline void write_tile(ushort* Khi, ushort* Klo, int tid,
                                  const shortx8 rh[4], const shortx8 rl[4]) {
#pragma unroll
    for (int i = 0; i < 4; ++i) {
        int c = tid + 256 * i;
        int r = c >> 3, s = c & 7;
        *(shortx8*)&Khi[r * LDK + s * 8] = rh[i];
        *(shortx8*)&Klo[r * LDK + s * 8] = rl[i];
    }
}

// ---- A-operand fragments: lane holds A[m=lane&31][k=(lane>>5)*8+j] ----------
__device__ inline void load_a(const ushort* __restrict__ qhi_row,
                              const ushort* __restrict__ qlo_row,
                              int half, shortx8 ah[4], shortx8 al[4]) {
#pragma unroll
    for (int ks = 0; ks < 4; ++ks) {
        ah[ks] = *(const shortx8*)&qhi_row[ks * 16 + half * 8];
        al[ks] = *(const shortx8*)&qlo_row[ks * 16 + half * 8];
    }
}

// ---------------------------------------------------------------------------
// Phase 1: per-row softmax stats (base-2), PARTIAL over an m-half.
// 1D grid 1024: idx = (bh + 32*ms) + 64*nblk -> blocks sharing a K-half are
// congruent mod 8 => same XCD (L2 locality). Lazy per-lane online stats.
// R7-measured config: __launch_bounds__(256,2) + register tile prefetch
// (77.6 us, WRITE 1 MB). The per-iter __syncthreads() doubles as a
// scheduling fence, so no cross-iteration load hoisting / spill here.
// ---------------------------------------------------------------------------
__global__ __launch_bounds__(256, 2) void stats_kernel(const ushort* __restrict__ qhi,
                                                       const ushort* __restrict__ qlo,
                                                       const ushort* __restrict__ khi,
                                                       const ushort* __restrict__ klo,
                                                       float* __restrict__ smax_p,
                                                       float* __restrict__ sden_p) {
    __shared__ ushort Khi[128 * LDK];
    __shared__ ushort Klo[128 * LDK];
    const int g    = blockIdx.x & 63;      // bh + 32*ms
    const int bh   = g & 31;
    const int ms   = g >> 5;               // m-split: tiles [ms*8, ms*8+8)
    const int n0   = (blockIdx.x >> 6) * 128;
    const int tid  = threadIdx.x;
    const int wave = tid >> 6, lane = tid & 63;
    const int half = lane >> 5, l31 = lane & 31;
    const size_t base = (size_t)bh * NN * DD;

    // A fragments: fixed rows for the whole kernel.
    shortx8 ah[4], al[4];
    {
        size_t ro = base + (size_t)(n0 + wave * 32 + l31) * DD;
        load_a(qhi + ro, qlo + ro, half, ah, al);
    }

    float m_run[16], d_run[16];
#pragma unroll
    for (int r = 0; r < 16; ++r) { m_run[r] = -INFINITY; d_run[r] = 0.f; }

    const ushort* khi_b = khi + base;
    const ushort* klo_b = klo + base;
    shortx8 rh[4], rl[4];
    load_tile(khi_b + (size_t)(ms * 8) * 8192, klo_b + (size_t)(ms * 8) * 8192, tid, rh, rl);

    for (int mti = 0; mti < 8; ++mti) {
        __syncthreads();                       // LDS consumers of prev tile done
        write_tile(Khi, Klo, tid, rh, rl);
        __syncthreads();
        if (mti < 7) {                         // prefetch next tile under compute
            size_t toff = (size_t)(ms * 8 + mti + 1) * 8192;
            load_tile(khi_b + toff, klo_b + toff, tid, rh, rl);
        }

        floatx16 acc[4];
#pragma unroll
        for (int t = 0; t < 4; ++t)
#pragma unroll
            for (int e = 0; e < 16; ++e) acc[t][e] = 0.f;

#pragma unroll
        for (int t = 0; t < 4; ++t) {
            const int mr = t * 32 + l31;
#pragma unroll
            for (int ks = 0; ks < 4; ++ks) {
                const int off = mr * LDK + ks * 16 + half * 8;
                shortx8 bhf = *(const shortx8*)&Khi[off];
                shortx8 blf = *(const shortx8*)&Klo[off];
                acc[t] = __builtin_amdgcn_mfma_f32_32x32x16_bf16(ah[ks], bhf, acc[t], 0, 0, 0);
                acc[t] = __builtin_amdgcn_mfma_f32_32x32x16_bf16(al[ks], bhf, acc[t], 0, 0, 0);
                acc[t] = __builtin_amdgcn_mfma_f32_32x32x16_bf16(ah[ks], blf, acc[t], 0, 0, 0);
            }
        }

        // Lazy per-lane online stats, base-2 domain.
#pragma unroll
        for (int r = 0; r < 16; ++r) {
            float tmax = fmaxf(fmaxf(acc[0][r], acc[1][r]), fmaxf(acc[2][r], acc[3][r]));
            float m_new = fmaxf(m_run[r], tmax);
            float s = fexp2(acc[0][r] - m_new) + fexp2(acc[1][r] - m_new)
                    + fexp2(acc[2][r] - m_new) + fexp2(acc[3][r] - m_new);
            d_run[r] = d_run[r] * fexp2(m_run[r] - m_new) + s;
            m_run[r] = m_new;
        }
    }

    // Cross-lane combine within each 32-lane half (rows differ across halves).
    float* smp = smax_p + ((size_t)ms * BH + bh) * NN;
    float* sdp = sden_p + ((size_t)ms * BH + bh) * NN;
#pragma unroll
    for (int r = 0; r < 16; ++r) {
        float M = m_run[r];
#pragma unroll
        for (int off = 1; off < 32; off <<= 1)
            M = fmaxf(M, __shfl_xor(M, off));
        float dd = d_run[r] * fexp2(m_run[r] - M);
#pragma unroll
        for (int off = 1; off < 32; off <<= 1)
            dd += __shfl_xor(dd, off);
        if (l31 == 0) {
            int row = n0 + wave * 32 + rowmap(r, half);
            smp[row] = M;
            sdp[row] = dd;
        }
    }
}

// ---------------------------------------------------------------------------
// Combine the two m-split partials (base-2): M=max, den combined; store 1/den.
// ---------------------------------------------------------------------------
__global__ __launch_bounds__(256) void combine_kernel(const float* __restrict__ smax_p,
                                                      const float* __restrict__ sden_p,
                                                      float* __restrict__ smaxC,
                                                      float* __restrict__ sinvC) {
    int idx = blockIdx.x * 256 + threadIdx.x;  // BHNN total
    float m0 = smax_p[idx], m1 = smax_p[BHNN + idx];
    float d0 = sden_p[idx], d1 = sden_p[BHNN + idx];
    float M = fmaxf(m0, m1);
    float den = d0 * fexp2(m0 - M) + d1 * fexp2(m1 - M);
    smaxC[idx] = M;
    sinvC[idx] = 1.0f / den;
}

// ---------------------------------------------------------------------------
// Phase 2: partial w[m] over an n-half. 1D grid 1024 with mod-8 XCD swizzle.
// Block owns 128 cols (K tile staged once); waves stride 32-row strips.
// #pragma unroll 1 on the strip loop: R5/R8/R9 all spilled exactly one
// 16-dword fragment set per iteration (WRITE_SIZE 133 MB, invariant to acc
// count) because the FULLY-UNROLLED barrier-free loop let the scheduler hoist
// future iterations' load_a clusters until the register file overflowed.
// A non-unrolled loop is a hoisting fence; body demand (~130 regs: 64 acc +
// 32 frags + temps) fits __launch_bounds__(256,3) without spill.
// Per-row (M,1/den) staged in LDS once (8 KB).
// ---------------------------------------------------------------------------
__global__ __launch_bounds__(256, 3) void wsum_kernel(const ushort* __restrict__ qhi,
                                                      const ushort* __restrict__ qlo,
                                                      const ushort* __restrict__ khi,
                                                      const ushort* __restrict__ klo,
                                                      const float* __restrict__ smaxC,
                                                      const float* __restrict__ sinvC,
                                                      float* __restrict__ wpart) {
    __shared__ ushort Khi[128 * LDK];
    __shared__ ushort Klo[128 * LDK];
    __shared__ float wred[4 * 128];
    __shared__ float Ms[1024];
    __shared__ float Is[1024];
    const int g    = blockIdx.x & 63;      // bh + 32*nz
    const int bh   = g & 31;
    const int nz   = g >> 5;               // n-split: rows [nz*1024, +1024)
    const int m0   = (blockIdx.x >> 6) * 128;
    const int tid  = threadIdx.x;
    const int wave = tid >> 6, lane = tid & 63;
    const int half = lane >> 5, l31 = lane & 31;
    const size_t base = (size_t)bh * NN * DD;

    {   // stage this block's K tile + row stats once
        shortx8 rh[4], rl[4];
        load_tile(khi + base + (size_t)m0 * 64, klo + base + (size_t)m0 * 64, tid, rh, rl);
        write_tile(Khi, Klo, tid, rh, rl);
        const float4* sm4 = (const float4*)(smaxC + (size_t)bh * NN + nz * 1024);
        const float4* si4 = (const float4*)(sinvC + (size_t)bh * NN + nz * 1024);
        *(float4*)&Ms[tid * 4] = sm4[tid];
        *(float4*)&Is[tid * 4] = si4[tid];
    }
    __syncthreads();

    float wacc[4] = {0.f, 0.f, 0.f, 0.f};

#pragma unroll 1
    for (int it = 0; it < 8; ++it) {       // NOT unrolled: stops load hoisting
        const int ls = wave + it * 4;      // local strip 0..31
        shortx8 ah[4], al[4];
        {
            size_t ro = base + (size_t)((nz * 32 + ls) * 32 + l31) * DD;
            load_a(qhi + ro, qlo + ro, half, ah, al);
        }

        floatx16 acc[4];
#pragma unroll
        for (int t = 0; t < 4; ++t)
#pragma unroll
            for (int e = 0; e < 16; ++e) acc[t][e] = 0.f;

#pragma unroll
        for (int t = 0; t < 4; ++t) {
            const int mr = t * 32 + l31;
#pragma unroll
            for (int ks = 0; ks < 4; ++ks) {
                const int off = mr * LDK + ks * 16 + half * 8;
                shortx8 bhf = *(const shortx8*)&Khi[off];
                shortx8 blf = *(const shortx8*)&Klo[off];
                acc[t] = __builtin_amdgcn_mfma_f32_32x32x16_bf16(ah[ks], bhf, acc[t], 0, 0, 0);
                acc[t] = __builtin_amdgcn_mfma_f32_32x32x16_bf16(al[ks], bhf, acc[t], 0, 0, 0);
                acc[t] = __builtin_amdgcn_mfma_f32_32x32x16_bf16(ah[ks], blf, acc[t], 0, 0, 0);
            }
        }

#pragma unroll
        for (int r = 0; r < 16; ++r) {
            const int lrow = ls * 32 + rowmap(r, half);   // broadcast LDS read
            float M   = Ms[lrow];
            float inv = Is[lrow];
#pragma unroll
            for (int t = 0; t < 4; ++t)
                wacc[t] += fexp2(acc[t][r] - M) * inv;
        }
    }

    // halves hold same cols, different rows: sum across halves, then waves.
#pragma unroll
    for (int t = 0; t < 4; ++t) wacc[t] += __shfl_xor(wacc[t], 32);
    if (half == 0) {
#pragma unroll
        for (int t = 0; t < 4; ++t) wred[wave * 128 + t * 32 + l31] = wacc[t];
    }
    __syncthreads();
    if (tid < 128) {
        float s = wred[tid] + wred[128 + tid] + wred[256 + tid] + wred[384 + tid];
        wpart[((size_t)nz * BH + bh) * NN + m0 + tid] = s;
    }
}

// ---------------------------------------------------------------------------
// Phase 3: out[b,h,m,d] = (w0[m]+w1[m]) * v[b,h,m,d]
// ---------------------------------------------------------------------------
__global__ __launch_bounds__(256) void out_kernel(const float* __restrict__ v,
                                                  const float* __restrict__ w0,
                                                  const float* __restrict__ w1,
                                                  float* __restrict__ out) {
    size_t gid = (size_t)blockIdx.x * 256 + threadIdx.x;  // float4 index
    const float4* v4 = (const float4*)v;
    float4* o4 = (float4*)out;
    float4 vv = v4[gid];
    float ww = w0[gid >> 4] + w1[gid >> 4];
    o4[gid] = make_float4(vv.x * ww, vv.y * ww, vv.z * ww, vv.w * ww);
}

extern "C" void kernel_launch(void* const* d_in, const int* in_sizes, int n_in,
                              void* d_out, int out_size, void* d_ws, size_t ws_size,
                              hipStream_t stream) {
    const float* q = (const float*)d_in[0];
    const float* k = (const float*)d_in[1];
    const float* v = (const float*)d_in[2];
    float* out = (float*)d_out;

    // Workspace (~35.7 MB), all fully rewritten each launch:
    ushort* qhi = (ushort*)d_ws;
    ushort* qlo = qhi + QK;
    ushort* khi = qlo + QK;
    ushort* klo = khi + QK;
    float* smax_p = (float*)(klo + QK);       // 2*BHNN
    float* sden_p = smax_p + 2 * BHNN;        // 2*BHNN
    float* smaxC  = sden_p + 2 * BHNN;        // BHNN
    float* sinvC  = smaxC + BHNN;             // BHNN
    float* wpart  = sinvC + BHNN;             // 2*BHNN

    convert_kernel<<<QK / 4 / 256, 256, 0, stream>>>((const float4*)q, (const float4*)k,
                                                     qhi, qlo, khi, klo);
    stats_kernel<<<1024, 256, 0, stream>>>(qhi, qlo, khi, klo, smax_p, sden_p);
    combine_kernel<<<BHNN / 256, 256, 0, stream>>>(smax_p, sden_p, smaxC, sinvC);
    wsum_kernel<<<1024, 256, 0, stream>>>(qhi, qlo, khi, klo, smaxC, sinvC, wpart);
    out_kernel<<<(BH * NN * DD / 4) / 256, 256, 0, stream>>>(v, wpart, wpart + BHNN, out);
}

// Round 11
// 222.612 us; speedup vs baseline: 1.4174x; 1.4174x over previous
//
#include <hip/hip_runtime.h>
#include <math.h>

// q,k,v: [B=2, H=16, N=2048, Dh=64] fp32.  BH = 32 independent heads.
#define BH 32
#define NN 2048
#define DD 64
#define BHNN (BH * NN)        // 65536 rows total
#define QK ((size_t)BH * NN * DD)  // 4,194,304 elems per tensor
#define LDK 72                // padded LDS row (ushort): stride 144B, conflict-free (measured 0)

// 8 * log2(e): logits produced in base-2 domain so all softmax exps are a bare
// v_exp_f32 (exp2). Softmax is invariant to the base change.
#define QSCALE 11.5415603f

typedef __attribute__((ext_vector_type(8)))  short shortx8;
typedef __attribute__((ext_vector_type(16))) float floatx16;

__device__ inline float fexp2(float x) { return __builtin_amdgcn_exp2f(x); }

// ---- bf16 split helpers (round-to-nearest-even) -----------------------------
__device__ inline unsigned short bf16_rn(float f) {
    unsigned int u = __builtin_bit_cast(unsigned int, f);
    u += 0x7fffu + ((u >> 16) & 1u);
    return (unsigned short)(u >> 16);
}
__device__ inline float bf16_to_f(unsigned short h) {
    return __builtin_bit_cast(float, (unsigned int)h << 16);
}
__device__ inline void split_bf16(float f, unsigned short& h, unsigned short& l) {
    h = bf16_rn(f);
    l = bf16_rn(f - bf16_to_f(h));
}

// C/D row for accumulator register r (0..15) given half = lane>>5 (verified R2).
__device__ inline int rowmap(int r, int half) {
    return (r & 3) + 8 * (r >> 2) + 4 * half;
}

// ---------------------------------------------------------------------------
// Pre-convert: q,k fp32 -> bf16 hi/lo arrays. QSCALE folded into q.
// ---------------------------------------------------------------------------
__global__ __launch_bounds__(256) void convert_kernel(const float4* __restrict__ q,
                                                      const float4* __restrict__ k,
                                                      ushort* __restrict__ qhi,
                                                      ushort* __restrict__ qlo,
                                                      ushort* __restrict__ khi,
                                                      ushort* __restrict__ klo) {
    size_t gid = (size_t)blockIdx.x * 256 + threadIdx.x;  // float4 index, QK/4 total
    float4 qa = q[gid];
    float4 ka = k[gid];
    ushort4 h, l;
    split_bf16(qa.x * QSCALE, h.x, l.x);
    split_bf16(qa.y * QSCALE, h.y, l.y);
    split_bf16(qa.z * QSCALE, h.z, l.z);
    split_bf16(qa.w * QSCALE, h.w, l.w);
    *(ushort4*)&qhi[gid * 4] = h;
    *(ushort4*)&qlo[gid * 4] = l;
    split_bf16(ka.x, h.x, l.x);
    split_bf16(ka.y, h.y, l.y);
    split_bf16(ka.z, h.z, l.z);
    split_bf16(ka.w, h.w, l.w);
    *(ushort4*)&khi[gid * 4] = h;
    *(ushort4*)&klo[gid * 4] = l;
}

// ---- tile staging: 128 rows x 64 cols bf16 (hi+lo), 16B chunks per thread ----
__device__ inline void load_tile(const ushort* __restrict__ khi_t,
                                 const ushort* __restrict__ klo_t,
                                 int tid, shortx8 rh[4], shortx8 rl[4]) {
#pragma unroll
    for (int i = 0; i < 4; ++i) {
        int c = tid + 256 * i;       // chunk 0..1023
        int r = c >> 3, s = c & 7;   // row, 16B slot
        rh[i] = *(const shortx8*)&khi_t[(size_t)r * 64 + s * 8];
        rl[i] = *(const shortx8*)&klo_t[(size_t)r * 64 + s * 8];
    }
}
__device__ inline void write_tile(ushort* Khi, ushort* Klo, int tid,
                                  const shortx8 rh[4], const shortx8 rl[4]) {
#pragma unroll
    for (int i = 0; i < 4; ++i) {
        int c = tid + 256 * i;
        int r = c >> 3, s = c & 7;
        *(shortx8*)&Khi[r * LDK + s * 8] = rh[i];
        *(shortx8*)&Klo[r * LDK + s * 8] = rl[i];
    }
}

// ---- A-operand fragments: lane holds A[m=lane&31][k=(lane>>5)*8+j] ----------
__device__ inline void load_a(const ushort* __restrict__ qhi_row,
                              const ushort* __restrict__ qlo_row,
                              int half, shortx8 ah[4], shortx8 al[4]) {
#pragma unroll
    for (int ks = 0; ks < 4; ++ks) {
        ah[ks] = *(const shortx8*)&qhi_row[ks * 16 + half * 8];
        al[ks] = *(const shortx8*)&qlo_row[ks * 16 + half * 8];
    }
}

// ---------------------------------------------------------------------------
// Phase 1: per-row softmax stats (base-2), PARTIAL over an m-half.
// 1D grid 1024: idx = (bh + 32*ms) + 64*nblk -> blocks sharing a K-half are
// congruent mod 8 => same XCD (L2 locality). Lazy per-lane online stats.
// R7-measured config: __launch_bounds__(256,2) + register tile prefetch
// (77.6 us, WRITE 1 MB). DO NOT raise to (256,3): spills (R6: 93 MB, R8 regr).
// ---------------------------------------------------------------------------
__global__ __launch_bounds__(256, 2) void stats_kernel(const ushort* __restrict__ qhi,
                                                       const ushort* __restrict__ qlo,
                                                       const ushort* __restrict__ khi,
                                                       const ushort* __restrict__ klo,
                                                       float* __restrict__ smax_p,
                                                       float* __restrict__ sden_p) {
    __shared__ ushort Khi[128 * LDK];
    __shared__ ushort Klo[128 * LDK];
    const int g    = blockIdx.x & 63;      // bh + 32*ms
    const int bh   = g & 31;
    const int ms   = g >> 5;               // m-split: tiles [ms*8, ms*8+8)
    const int n0   = (blockIdx.x >> 6) * 128;
    const int tid  = threadIdx.x;
    const int wave = tid >> 6, lane = tid & 63;
    const int half = lane >> 5, l31 = lane & 31;
    const size_t base = (size_t)bh * NN * DD;

    // A fragments: fixed rows for the whole kernel.
    shortx8 ah[4], al[4];
    {
        size_t ro = base + (size_t)(n0 + wave * 32 + l31) * DD;
        load_a(qhi + ro, qlo + ro, half, ah, al);
    }

    float m_run[16], d_run[16];
#pragma unroll
    for (int r = 0; r < 16; ++r) { m_run[r] = -INFINITY; d_run[r] = 0.f; }

    const ushort* khi_b = khi + base;
    const ushort* klo_b = klo + base;
    shortx8 rh[4], rl[4];
    load_tile(khi_b + (size_t)(ms * 8) * 8192, klo_b + (size_t)(ms * 8) * 8192, tid, rh, rl);

    for (int mti = 0; mti < 8; ++mti) {
        __syncthreads();                       // LDS consumers of prev tile done
        write_tile(Khi, Klo, tid, rh, rl);
        __syncthreads();
        if (mti < 7) {                         // prefetch next tile under compute
            size_t toff = (size_t)(ms * 8 + mti + 1) * 8192;
            load_tile(khi_b + toff, klo_b + toff, tid, rh, rl);
        }

        floatx16 acc[4];
#pragma unroll
        for (int t = 0; t < 4; ++t)
#pragma unroll
            for (int e = 0; e < 16; ++e) acc[t][e] = 0.f;

#pragma unroll
        for (int t = 0; t < 4; ++t) {
            const int mr = t * 32 + l31;
#pragma unroll
            for (int ks = 0; ks < 4; ++ks) {
                const int off = mr * LDK + ks * 16 + half * 8;
                shortx8 bhf = *(const shortx8*)&Khi[off];
                shortx8 blf = *(const shortx8*)&Klo[off];
                acc[t] = __builtin_amdgcn_mfma_f32_32x32x16_bf16(ah[ks], bhf, acc[t], 0, 0, 0);
                acc[t] = __builtin_amdgcn_mfma_f32_32x32x16_bf16(al[ks], bhf, acc[t], 0, 0, 0);
                acc[t] = __builtin_amdgcn_mfma_f32_32x32x16_bf16(ah[ks], blf, acc[t], 0, 0, 0);
            }
        }

        // Lazy per-lane online stats, base-2 domain.
#pragma unroll
        for (int r = 0; r < 16; ++r) {
            float tmax = fmaxf(fmaxf(acc[0][r], acc[1][r]), fmaxf(acc[2][r], acc[3][r]));
            float m_new = fmaxf(m_run[r], tmax);
            float s = fexp2(acc[0][r] - m_new) + fexp2(acc[1][r] - m_new)
                    + fexp2(acc[2][r] - m_new) + fexp2(acc[3][r] - m_new);
            d_run[r] = d_run[r] * fexp2(m_run[r] - m_new) + s;
            m_run[r] = m_new;
        }
    }

    // Cross-lane combine within each 32-lane half (rows differ across halves).
    float* smp = smax_p + ((size_t)ms * BH + bh) * NN;
    float* sdp = sden_p + ((size_t)ms * BH + bh) * NN;
#pragma unroll
    for (int r = 0; r < 16; ++r) {
        float M = m_run[r];
#pragma unroll
        for (int off = 1; off < 32; off <<= 1)
            M = fmaxf(M, __shfl_xor(M, off));
        float dd = d_run[r] * fexp2(m_run[r] - M);
#pragma unroll
        for (int off = 1; off < 32; off <<= 1)
            dd += __shfl_xor(dd, off);
        if (l31 == 0) {
            int row = n0 + wave * 32 + rowmap(r, half);
            smp[row] = M;
            sdp[row] = dd;
        }
    }
}

// ---------------------------------------------------------------------------
// Combine the two m-split partials (base-2): M=max, den combined; store 1/den.
// ---------------------------------------------------------------------------
__global__ __launch_bounds__(256) void combine_kernel(const float* __restrict__ smax_p,
                                                      const float* __restrict__ sden_p,
                                                      float* __restrict__ smaxC,
                                                      float* __restrict__ sinvC) {
    int idx = blockIdx.x * 256 + threadIdx.x;  // BHNN total
    float m0 = smax_p[idx], m1 = smax_p[BHNN + idx];
    float d0 = sden_p[idx], d1 = sden_p[BHNN + idx];
    float M = fmaxf(m0, m1);
    float den = d0 * fexp2(m0 - M) + d1 * fexp2(m1 - M);
    smaxC[idx] = M;
    sinvC[idx] = 1.0f / den;
}

// ---------------------------------------------------------------------------
// Phase 2: partial w[m] over an n-half. 1D grid 1024 with mod-8 XCD swizzle.
// Block owns 128 cols (K tile staged once); waves stride 32-row strips.
// __launch_bounds__(256,2), FULL unroll — the R7-measured clean regime
// (WRITE ~1 MB, wsum <= 77 us). The (256,3) wall is measured and real:
// R5 133 MB / R8 135 MB / R9 133 MB (acc-split) / R10 74 MB (unroll-1,
// slower) — every 3-waves/SIMD variant spills; do not retry without a
// fundamentally smaller per-wave tile. Per-row (M,1/den) staged in LDS once.
// ---------------------------------------------------------------------------
__global__ __launch_bounds__(256, 2) void wsum_kernel(const ushort* __restrict__ qhi,
                                                      const ushort* __restrict__ qlo,
                                                      const ushort* __restrict__ khi,
                                                      const ushort* __restrict__ klo,
                                                      const float* __restrict__ smaxC,
                                                      const float* __restrict__ sinvC,
                                                      float* __restrict__ wpart) {
    __shared__ ushort Khi[128 * LDK];
    __shared__ ushort Klo[128 * LDK];
    __shared__ float wred[4 * 128];
    __shared__ float Ms[1024];
    __shared__ float Is[1024];
    const int g    = blockIdx.x & 63;      // bh + 32*nz
    const int bh   = g & 31;
    const int nz   = g >> 5;               // n-split: rows [nz*1024, +1024)
    const int m0   = (blockIdx.x >> 6) * 128;
    const int tid  = threadIdx.x;
    const int wave = tid >> 6, lane = tid & 63;
    const int half = lane >> 5, l31 = lane & 31;
    const size_t base = (size_t)bh * NN * DD;

    {   // stage this block's K tile + row stats once
        shortx8 rh[4], rl[4];
        load_tile(khi + base + (size_t)m0 * 64, klo + base + (size_t)m0 * 64, tid, rh, rl);
        write_tile(Khi, Klo, tid, rh, rl);
        const float4* sm4 = (const float4*)(smaxC + (size_t)bh * NN + nz * 1024);
        const float4* si4 = (const float4*)(sinvC + (size_t)bh * NN + nz * 1024);
        *(float4*)&Ms[tid * 4] = sm4[tid];
        *(float4*)&Is[tid * 4] = si4[tid];
    }
    __syncthreads();

    float wacc[4] = {0.f, 0.f, 0.f, 0.f};

#pragma unroll
    for (int it = 0; it < 8; ++it) {
        const int ls = wave + it * 4;      // local strip 0..31
        shortx8 ah[4], al[4];
        {
            size_t ro = base + (size_t)((nz * 32 + ls) * 32 + l31) * DD;
            load_a(qhi + ro, qlo + ro, half, ah, al);
        }

        floatx16 acc[4];
#pragma unroll
        for (int t = 0; t < 4; ++t)
#pragma unroll
            for (int e = 0; e < 16; ++e) acc[t][e] = 0.f;

#pragma unroll
        for (int t = 0; t < 4; ++t) {
            const int mr = t * 32 + l31;
#pragma unroll
            for (int ks = 0; ks < 4; ++ks) {
                const int off = mr * LDK + ks * 16 + half * 8;
                shortx8 bhf = *(const shortx8*)&Khi[off];
                shortx8 blf = *(const shortx8*)&Klo[off];
                acc[t] = __builtin_amdgcn_mfma_f32_32x32x16_bf16(ah[ks], bhf, acc[t], 0, 0, 0);
                acc[t] = __builtin_amdgcn_mfma_f32_32x32x16_bf16(al[ks], bhf, acc[t], 0, 0, 0);
                acc[t] = __builtin_amdgcn_mfma_f32_32x32x16_bf16(ah[ks], blf, acc[t], 0, 0, 0);
            }
        }

#pragma unroll
        for (int r = 0; r < 16; ++r) {
            const int lrow = ls * 32 + rowmap(r, half);   // broadcast LDS read
            float M   = Ms[lrow];
            float inv = Is[lrow];
#pragma unroll
            for (int t = 0; t < 4; ++t)
                wacc[t] += fexp2(acc[t][r] - M) * inv;
        }
    }

    // halves hold same cols, different rows: sum across halves, then waves.
#pragma unroll
    for (int t = 0; t < 4; ++t) wacc[t] += __shfl_xor(wacc[t], 32);
    if (half == 0) {
#pragma unroll
        for (int t = 0; t < 4; ++t) wred[wave * 128 + t * 32 + l31] = wacc[t];
    }
    __syncthreads();
    if (tid < 128) {
        float s = wred[tid] + wred[128 + tid] + wred[256 + tid] + wred[384 + tid];
        wpart[((size_t)nz * BH + bh) * NN + m0 + tid] = s;
    }
}

// ---------------------------------------------------------------------------
// Phase 3: out[b,h,m,d] = (w0[m]+w1[m]) * v[b,h,m,d]
// ---------------------------------------------------------------------------
__global__ __launch_bounds__(256) void out_kernel(const float* __restrict__ v,
                                                  const float* __restrict__ w0,
                                                  const float* __restrict__ w1,
                                                  float* __restrict__ out) {
    size_t gid = (size_t)blockIdx.x * 256 + threadIdx.x;  // float4 index
    const float4* v4 = (const float4*)v;
    float4* o4 = (float4*)out;
    float4 vv = v4[gid];
    float ww = w0[gid >> 4] + w1[gid >> 4];
    o4[gid] = make_float4(vv.x * ww, vv.y * ww, vv.z * ww, vv.w * ww);
}

extern "C" void kernel_launch(void* const* d_in, const int* in_sizes, int n_in,
                              void* d_out, int out_size, void* d_ws, size_t ws_size,
                              hipStream_t stream) {
    const float* q = (const float*)d_in[0];
    const float* k = (const float*)d_in[1];
    const float* v = (const float*)d_in[2];
    float* out = (float*)d_out;

    // Workspace (~35.7 MB), all fully rewritten each launch:
    ushort* qhi = (ushort*)d_ws;
    ushort* qlo = qhi + QK;
    ushort* khi = qlo + QK;
    ushort* klo = khi + QK;
    float* smax_p = (float*)(klo + QK);       // 2*BHNN
    float* sden_p = smax_p + 2 * BHNN;        // 2*BHNN
    float* smaxC  = sden_p + 2 * BHNN;        // BHNN
    float* sinvC  = smaxC + BHNN;             // BHNN
    float* wpart  = sinvC + BHNN;             // 2*BHNN

    convert_kernel<<<QK / 4 / 256, 256, 0, stream>>>((const float4*)q, (const float4*)k,
                                                     qhi, qlo, khi, klo);
    stats_kernel<<<1024, 256, 0, stream>>>(qhi, qlo, khi, klo, smax_p, sden_p);
    combine_kernel<<<BHNN / 256, 256, 0, stream>>>(smax_p, sden_p, smaxC, sinvC);
    wsum_kernel<<<1024, 256, 0, stream>>>(qhi, qlo, khi, klo, smaxC, sinvC, wpart);
    out_kernel<<<(BH * NN * DD / 4) / 256, 256, 0, stream>>>(v, wpart, wpart + BHNN, out);
}